// Round 8
// baseline (385.602 us; speedup 1.0000x reference)
//
#include <hip/hip_runtime.h>
#include <math.h>

#define BB 32768
#define DD 512
#define CC 527
#define NTW 17        // col-tiles per wave -> 272 cols
#define NCOL 544
#define BM 32         // rows per block = 2 row-tiles x 16
#define CHW 272

typedef __attribute__((ext_vector_type(8))) short bf16x8;
typedef __attribute__((ext_vector_type(4))) short bf16x4;
typedef __attribute__((ext_vector_type(4))) float f32x4;

// Named-SSA accumulators only (R6 lesson: f32x4 arrays -> scratch).
#define FOREACH_T(OP) OP(0) OP(1) OP(2) OP(3) OP(4) OP(5) OP(6) OP(7) OP(8) \
  OP(9) OP(10) OP(11) OP(12) OP(13) OP(14) OP(15) OP(16)

#if __has_builtin(__builtin_amdgcn_exp2f)
#define EXP2F(v) __builtin_amdgcn_exp2f(v)
#else
#define EXP2F(v) exp2f(v)
#endif
#if __has_builtin(__builtin_amdgcn_logf)
#define LOG2F(v) __builtin_amdgcn_logf(v)
#else
#define LOG2F(v) __log2f(v)
#endif

__device__ __forceinline__ short f2bf(float f) {  // fp32 -> bf16 RNE
  unsigned u = __float_as_uint(f);
  u += 0x7fffu + ((u >> 16) & 1u);
  return (short)(u >> 16);
}
__device__ __forceinline__ bf16x8 pack8(f32x4 a, f32x4 b) {
  bf16x8 v;
  v[0]=f2bf(a.x); v[1]=f2bf(a.y); v[2]=f2bf(a.z); v[3]=f2bf(a.w);
  v[4]=f2bf(b.x); v[5]=f2bf(b.y); v[6]=f2bf(b.z); v[7]=f2bf(b.w);
  return v;
}

// Block = 128 threads = 2 waves; wave wv owns cols [wv*272, wv*272+272).
// No LDS / no barriers in the K-loop: B-frags stream from L2 (W bf16 = 557KB,
// L2-resident), A-frags from x with manual double-buffer. MFMA<->load overlap
// is left to the compiler via vmcnt (possible only because barriers are gone).
template<bool PRE>
__global__ __launch_bounds__(128, 2)
void fused_mfma_bce_topk(const float* __restrict__ x, const float* __restrict__ y,
                         const float* __restrict__ W, const short* __restrict__ Wbf,
                         const float* __restrict__ bias, const float* __restrict__ pw,
                         float* __restrict__ accum) {
  __shared__ int   kcL[2][BM];
  __shared__ int   cntL[2][BM];
  __shared__ int   hitL[2][BM];
  __shared__ float redL[2], redS[2];

  const int tid  = threadIdx.x;
  const int wv   = tid >> 6;           // col half
  const int lane = tid & 63;
  const int cl   = lane & 15, quad = lane >> 4;
  const int row0 = blockIdx.x * BM;
  const int chbase = wv * CHW;

#define DECL(t) f32x4 P##t = (f32x4){0.f,0.f,0.f,0.f}; \
                f32x4 Q##t = (f32x4){0.f,0.f,0.f,0.f};
  FOREACH_T(DECL)
#undef DECL

  // ---------------- LDS-free MFMA GEMM over K = 512 ----------------
  const float* ax    = x + (size_t)(row0 + cl) * DD + quad * 8;
  const short* wbase = Wbf + (size_t)(chbase + cl) * DD + quad * 8;

  f32x4 pa0 = __builtin_nontemporal_load((const f32x4*)ax);
  f32x4 pa1 = __builtin_nontemporal_load((const f32x4*)(ax + 4));
  f32x4 pb0 = __builtin_nontemporal_load((const f32x4*)(ax + 16 * DD));
  f32x4 pb1 = __builtin_nontemporal_load((const f32x4*)(ax + 16 * DD + 4));

#pragma unroll 2
  for (int k0 = 0; k0 < DD; k0 += 32) {
    bf16x8 afP = pack8(pa0, pa1);
    bf16x8 afQ = pack8(pb0, pb1);
    if (k0 + 32 < DD) {   // prefetch next A chunk (HBM latency hiding)
      const float* nx = ax + k0 + 32;
      pa0 = __builtin_nontemporal_load((const f32x4*)nx);
      pa1 = __builtin_nontemporal_load((const f32x4*)(nx + 4));
      pb0 = __builtin_nontemporal_load((const f32x4*)(nx + 16 * DD));
      pb1 = __builtin_nontemporal_load((const f32x4*)(nx + 16 * DD + 4));
    }
    if (PRE) {
#define MFS(t) { \
      bf16x8 bfr = *(const bf16x8*)(wbase + k0 + (size_t)(t) * 16 * DD); \
      P##t = __builtin_amdgcn_mfma_f32_16x16x32_bf16(afP, bfr, P##t, 0, 0, 0); \
      Q##t = __builtin_amdgcn_mfma_f32_16x16x32_bf16(afQ, bfr, Q##t, 0, 0, 0); }
      FOREACH_T(MFS)
#undef MFS
    } else {
#define MFSF(t) { \
      int col = chbase + (t) * 16 + cl; \
      bf16x8 bfr = {0,0,0,0,0,0,0,0}; \
      if (col < CC) { \
        const float* wp = W + (size_t)col * DD + k0 + quad * 8; \
        bfr = pack8(*(const f32x4*)wp, *(const f32x4*)(wp + 4)); \
      } \
      P##t = __builtin_amdgcn_mfma_f32_16x16x32_bf16(afP, bfr, P##t, 0, 0, 0); \
      Q##t = __builtin_amdgcn_mfma_f32_16x16x32_bf16(afQ, bfr, Q##t, 0, 0, 0); }
      FOREACH_T(MFSF)
#undef MFSF
    }
  }

  // ---------------- Epilogue ----------------
  // C/D: col = chbase + t*16 + cl ; P rows = row0+quad*4+r ; Q rows = +16
  const size_t gP = (size_t)(row0 + quad * 4);
  const size_t gQ = gP + 16;
  float lossloc = 0.f;
  unsigned ymP[4] = {0u,0u,0u,0u}, ymQ[4] = {0u,0u,0u,0u};

#define EPI(t) { \
    int col = chbase + (t) * 16 + cl; \
    bool cv = (col < CC); \
    float bt = cv ? bias[col] : 0.f; \
    float pt = cv ? pw[col]   : 1.f; \
    _Pragma("unroll") \
    for (int r = 0; r < 4; ++r) { \
      float zP = P##t[r] + bt, zQ = Q##t[r] + bt; \
      if (cv) { \
        float yvP = __builtin_nontemporal_load(&y[(gP + r) * CC + col]); \
        float yvQ = __builtin_nontemporal_load(&y[(gQ + r) * CC + col]); \
        float lP = LOG2F(1.f + EXP2F(fabsf(zP) * -1.4426950408889634f)) * 0.6931471805599453f; \
        float lQ = LOG2F(1.f + EXP2F(fabsf(zQ) * -1.4426950408889634f)) * 0.6931471805599453f; \
        float spP = fmaxf(zP, 0.f) + lP, spQ = fmaxf(zQ, 0.f) + lQ; \
        lossloc += pt * yvP * (spP - zP) + (1.f - yvP) * spP; \
        lossloc += pt * yvQ * (spQ - zQ) + (1.f - yvQ) * spQ; \
        if (yvP > 0.5f) ymP[r] |= (1u << (t)); \
        if (yvQ > 0.5f) ymQ[r] |= (1u << (t)); \
        P##t[r] = zP; Q##t[r] = zQ; \
      } else { P##t[r] = -1e30f; Q##t[r] = -1e30f; } \
    } }
  FOREACH_T(EPI)
#undef EPI

  // per-row positive counts: popc + 16-lane reduce (2 rows per u32), LDS combine
  unsigned kP01 = (unsigned)__popc(ymP[0]) | ((unsigned)__popc(ymP[1]) << 16);
  unsigned kP23 = (unsigned)__popc(ymP[2]) | ((unsigned)__popc(ymP[3]) << 16);
  unsigned kQ01 = (unsigned)__popc(ymQ[0]) | ((unsigned)__popc(ymQ[1]) << 16);
  unsigned kQ23 = (unsigned)__popc(ymQ[2]) | ((unsigned)__popc(ymQ[3]) << 16);
#pragma unroll
  for (int m = 1; m <= 8; m <<= 1) {
    kP01 += __shfl_xor(kP01, m, 64); kP23 += __shfl_xor(kP23, m, 64);
    kQ01 += __shfl_xor(kQ01, m, 64); kQ23 += __shfl_xor(kQ23, m, 64);
  }
  if (cl == 0) {
    kcL[wv][quad * 4 + 0] = (int)(kP01 & 0xffffu);
    kcL[wv][quad * 4 + 1] = (int)(kP01 >> 16);
    kcL[wv][quad * 4 + 2] = (int)(kP23 & 0xffffu);
    kcL[wv][quad * 4 + 3] = (int)(kP23 >> 16);
    kcL[wv][16 + quad * 4 + 0] = (int)(kQ01 & 0xffffu);
    kcL[wv][16 + quad * 4 + 1] = (int)(kQ01 >> 16);
    kcL[wv][16 + quad * 4 + 2] = (int)(kQ23 & 0xffffu);
    kcL[wv][16 + quad * 4 + 3] = (int)(kQ23 >> 16);
  }
  __syncthreads();
  int kr[8];
#pragma unroll
  for (int r = 0; r < 4; ++r) {
    kr[r]     = kcL[0][quad * 4 + r]      + kcL[1][quad * 4 + r];
    kr[4 + r] = kcL[0][16 + quad * 4 + r] + kcL[1][16 + quad * 4 + r];
  }

  // Bisection: per-row threshold with |{z > th}| == k  (27 iters over [-32,32])
  float lo[8], hi[8], th[8];
  bool fnd[8];
#pragma unroll
  for (int i = 0; i < 8; ++i) { lo[i] = -32.f; hi[i] = 32.f; th[i] = 0.f; fnd[i] = false; }

  for (int it = 0; it < 27; ++it) {
    float tmv[8];
#pragma unroll
    for (int i = 0; i < 8; ++i) tmv[i] = 0.5f * (lo[i] + hi[i]);
    int c[8] = {0,0,0,0,0,0,0,0};
#define CNT(t) { _Pragma("unroll") for (int r = 0; r < 4; ++r) { \
      c[r]     += (P##t[r] > tmv[r])     ? 1 : 0; \
      c[4 + r] += (Q##t[r] > tmv[4 + r]) ? 1 : 0; } }
    FOREACH_T(CNT)
#undef CNT
    unsigned pP01 = (unsigned)c[0] | ((unsigned)c[1] << 16);
    unsigned pP23 = (unsigned)c[2] | ((unsigned)c[3] << 16);
    unsigned pQ01 = (unsigned)c[4] | ((unsigned)c[5] << 16);
    unsigned pQ23 = (unsigned)c[6] | ((unsigned)c[7] << 16);
#pragma unroll
    for (int m = 1; m <= 8; m <<= 1) {
      pP01 += __shfl_xor(pP01, m, 64); pP23 += __shfl_xor(pP23, m, 64);
      pQ01 += __shfl_xor(pQ01, m, 64); pQ23 += __shfl_xor(pQ23, m, 64);
    }
    __syncthreads();   // previous iteration's cntL reads done before overwrite
    if (cl == 0) {
      cntL[wv][quad * 4 + 0] = (int)(pP01 & 0xffffu);
      cntL[wv][quad * 4 + 1] = (int)(pP01 >> 16);
      cntL[wv][quad * 4 + 2] = (int)(pP23 & 0xffffu);
      cntL[wv][quad * 4 + 3] = (int)(pP23 >> 16);
      cntL[wv][16 + quad * 4 + 0] = (int)(pQ01 & 0xffffu);
      cntL[wv][16 + quad * 4 + 1] = (int)(pQ01 >> 16);
      cntL[wv][16 + quad * 4 + 2] = (int)(pQ23 & 0xffffu);
      cntL[wv][16 + quad * 4 + 3] = (int)(pQ23 >> 16);
    }
    __syncthreads();
#pragma unroll
    for (int i = 0; i < 8; ++i) {
      int lr = (i < 4) ? (quad * 4 + i) : (16 + quad * 4 + (i - 4));
      int tot = cntL[0][lr] + cntL[1][lr];
      if (!fnd[i]) {
        if (tot == kr[i])                          { th[i] = tmv[i]; fnd[i] = true; }
        else if (tmv[i] <= lo[i] || tmv[i] >= hi[i]) { th[i] = lo[i]; fnd[i] = true; }
        else if (tot > kr[i])                      lo[i] = tmv[i];
        else                                       hi[i] = tmv[i];
      }
    }
  }
#pragma unroll
  for (int i = 0; i < 8; ++i) if (!fnd[i]) th[i] = lo[i];

  // hits among positives
  int c[8] = {0,0,0,0,0,0,0,0};
#define HIT(t) { _Pragma("unroll") for (int r = 0; r < 4; ++r) { \
    if (((ymP[r] >> (t)) & 1u) && P##t[r] > th[r])     c[r]++; \
    if (((ymQ[r] >> (t)) & 1u) && Q##t[r] > th[4 + r]) c[4 + r]++; } }
  FOREACH_T(HIT)
#undef HIT
  unsigned hP01 = (unsigned)c[0] | ((unsigned)c[1] << 16);
  unsigned hP23 = (unsigned)c[2] | ((unsigned)c[3] << 16);
  unsigned hQ01 = (unsigned)c[4] | ((unsigned)c[5] << 16);
  unsigned hQ23 = (unsigned)c[6] | ((unsigned)c[7] << 16);
#pragma unroll
  for (int m = 1; m <= 8; m <<= 1) {
    hP01 += __shfl_xor(hP01, m, 64); hP23 += __shfl_xor(hP23, m, 64);
    hQ01 += __shfl_xor(hQ01, m, 64); hQ23 += __shfl_xor(hQ23, m, 64);
  }
  __syncthreads();   // hitL fresh
  if (cl == 0) {
    hitL[wv][quad * 4 + 0] = (int)(hP01 & 0xffffu);
    hitL[wv][quad * 4 + 1] = (int)(hP01 >> 16);
    hitL[wv][quad * 4 + 2] = (int)(hP23 & 0xffffu);
    hitL[wv][quad * 4 + 3] = (int)(hP23 >> 16);
    hitL[wv][16 + quad * 4 + 0] = (int)(hQ01 & 0xffffu);
    hitL[wv][16 + quad * 4 + 1] = (int)(hQ01 >> 16);
    hitL[wv][16 + quad * 4 + 2] = (int)(hQ23 & 0xffffu);
    hitL[wv][16 + quad * 4 + 3] = (int)(hQ23 >> 16);
  }
  __syncthreads();
  float scoreloc = 0.f;
  if (wv == 0 && cl == 0) {
#pragma unroll
    for (int i = 0; i < 8; ++i) {
      int lr = (i < 4) ? (quad * 4 + i) : (16 + quad * 4 + (i - 4));
      int hits = hitL[0][lr] + hitL[1][lr];
      if (hits > kr[i]) hits = kr[i];   // tie/exhaustion clamp
      scoreloc += (float)hits / (float)kr[i];
    }
  }

  // Block reduction -> one global atomic per block per output
#pragma unroll
  for (int m = 1; m < 64; m <<= 1) {
    lossloc  += __shfl_xor(lossloc, m, 64);
    scoreloc += __shfl_xor(scoreloc, m, 64);
  }
  if (lane == 0) { redL[wv] = lossloc; redS[wv] = scoreloc; }
  __syncthreads();
  if (tid == 0) {
    atomicAdd(&accum[0], redL[0] + redL[1]);
    atomicAdd(&accum[1], redS[0] + redS[1]);
  }
}

__global__ void wcvt_kernel(const float* __restrict__ W, short* __restrict__ Wbf) {
  int idx = (blockIdx.x * 256 + threadIdx.x) * 4;   // elem in [544*512]
  int row = idx >> 9;
  bf16x4 v = {0, 0, 0, 0};
  if (row < CC) {
    f32x4 f = *(const f32x4*)(W + idx);
    v[0]=f2bf(f.x); v[1]=f2bf(f.y); v[2]=f2bf(f.z); v[3]=f2bf(f.w);
  }
  *(bf16x4*)(Wbf + idx) = v;
}

__global__ void init_ws_kernel(float* ws) {
  ws[0] = 0.f;
  ws[1] = 0.f;
}

__global__ void finalize_kernel(const float* __restrict__ ws, float* __restrict__ out) {
  out[0] = (float)((double)ws[0] / ((double)BB * (double)CC));
  out[1] = (float)((double)ws[1] / (double)BB);
}

extern "C" void kernel_launch(void* const* d_in, const int* in_sizes, int n_in,
                              void* d_out, int out_size, void* d_ws, size_t ws_size,
                              hipStream_t stream) {
  const float* x  = (const float*)d_in[0];
  const float* y  = (const float*)d_in[1];
  const float* W  = (const float*)d_in[2];
  const float* b  = (const float*)d_in[3];
  const float* pw = (const float*)d_in[4];
  float* out = (float*)d_out;
  float* ws  = (float*)d_ws;
  short* Wbf = (short*)((char*)d_ws + 64);

  const size_t need = 64 + (size_t)NCOL * DD * 2;
  const bool pre = (ws_size >= need);

  init_ws_kernel<<<dim3(1), dim3(1), 0, stream>>>(ws);
  if (pre) {
    wcvt_kernel<<<dim3(NCOL * DD / 1024), dim3(256), 0, stream>>>(W, Wbf);
    fused_mfma_bce_topk<true><<<dim3(BB / BM), dim3(128), 0, stream>>>(
        x, y, W, Wbf, b, pw, ws);
  } else {
    fused_mfma_bce_topk<false><<<dim3(BB / BM), dim3(128), 0, stream>>>(
        x, y, W, Wbf, b, pw, ws);
  }
  finalize_kernel<<<dim3(1), dim3(1), 0, stream>>>(ws, out);
}

// Round 9
// 348.179 us; speedup vs baseline: 1.1075x; 1.1075x over previous
//
#include <hip/hip_runtime.h>
#include <math.h>

#define BB 32768
#define DD 512
#define CC 527
#define NCOLP 576   // padded W cols: 36 tiles of 16 -> uniform 9 tiles per col-group
#define BM 32       // rows per block (2 row-groups x 16)
#define ZST 532     // LDS z row stride (floats)

typedef __attribute__((ext_vector_type(8))) short bf16x8;
typedef __attribute__((ext_vector_type(4))) short bf16x4;
typedef __attribute__((ext_vector_type(4))) float f32x4;

// Named-SSA accumulators (R6 lesson: f32x4 arrays never promote -> scratch).
#define FJ(OP) OP(0) OP(1) OP(2) OP(3) OP(4) OP(5) OP(6) OP(7) OP(8)
#define FRJ_R(OP, r) OP(r,0) OP(r,1) OP(r,2) OP(r,3) OP(r,4) OP(r,5) OP(r,6) OP(r,7) OP(r,8)
#define FRJ(OP) FRJ_R(OP,0) FRJ_R(OP,1) FRJ_R(OP,2) FRJ_R(OP,3)

#if __has_builtin(__builtin_amdgcn_exp2f)
#define EXP2F(v) __builtin_amdgcn_exp2f(v)
#else
#define EXP2F(v) exp2f(v)
#endif
#if __has_builtin(__builtin_amdgcn_logf)
#define LOG2F(v) __builtin_amdgcn_logf(v)
#else
#define LOG2F(v) __log2f(v)
#endif

__device__ __forceinline__ short f2bf(float f) {  // fp32 -> bf16 RNE
  unsigned u = __float_as_uint(f);
  u += 0x7fffu + ((u >> 16) & 1u);
  return (short)(u >> 16);
}
__device__ __forceinline__ bf16x8 pack8(f32x4 a, f32x4 b) {
  bf16x8 v;
  v[0]=f2bf(a.x); v[1]=f2bf(a.y); v[2]=f2bf(a.z); v[3]=f2bf(a.w);
  v[4]=f2bf(b.x); v[5]=f2bf(b.y); v[6]=f2bf(b.z); v[7]=f2bf(b.w);
  return v;
}

// Block = 512 thr = 8 waves = 2 row-groups x 4 col-groups. Wave: 16 rows x 9
// interleaved col-tiles (t = cg + 4j) -> acc only 36 regs. launch_bounds(512,4)
// caps 128 regs/thread -> 16 waves/CU (R6-R8 plateaued at ~7 waves/CU because
// acc alone was 136 regs). K-loop: no LDS, no barriers; B streams from L2.
// Epilogue: z -> LDS once, then each wave owns 4 whole rows (in-wave bisection,
// no barriers, coalesced y).
template<bool PRE>
__global__ __launch_bounds__(512, 4)
void fused_mfma_bce_topk(const float* __restrict__ x, const float* __restrict__ y,
                         const float* __restrict__ W, const short* __restrict__ Wbf,
                         const float* __restrict__ bias, const float* __restrict__ pw,
                         float* __restrict__ accum) {
  __shared__ float zs[BM][ZST];   // 68,096 B
  __shared__ float redL[8], redS[8];

  const int tid  = threadIdx.x;
  const int w    = tid >> 6, lane = tid & 63;
  const int cl   = lane & 15, quad = lane >> 4;
  const int rg   = w >> 2, cg = w & 3;
  const int row0 = blockIdx.x * BM;

#define DECL(j) f32x4 A##j = (f32x4){0.f, 0.f, 0.f, 0.f};
  FJ(DECL)
#undef DECL

  // ---------------- barrier-free MFMA GEMM over K = 512 ----------------
  const float* ax = x + (size_t)(row0 + rg * 16 + cl) * DD + quad * 8;
  f32x4 pa0 = *(const f32x4*)(ax);
  f32x4 pa1 = *(const f32x4*)(ax + 4);

  for (int k0 = 0; k0 < DD; k0 += 32) {
    bf16x8 af = pack8(pa0, pa1);
    if (k0 + 32 < DD) {
      pa0 = *(const f32x4*)(ax + k0 + 32);
      pa1 = *(const f32x4*)(ax + k0 + 36);
    }
    if (PRE) {
#define MFS(j) { \
      bf16x8 bfr = *(const bf16x8*)(Wbf + (size_t)((cg + 4*(j)) * 16 + cl) * DD + k0 + quad * 8); \
      A##j = __builtin_amdgcn_mfma_f32_16x16x32_bf16(af, bfr, A##j, 0, 0, 0); }
      FJ(MFS)
#undef MFS
    } else {
#define MFSF(j) { \
      int col = (cg + 4*(j)) * 16 + cl; \
      bf16x8 bfr = {0,0,0,0,0,0,0,0}; \
      if (col < CC) { \
        const float* wp = W + (size_t)col * DD + k0 + quad * 8; \
        bfr = pack8(*(const f32x4*)wp, *(const f32x4*)(wp + 4)); \
      } \
      A##j = __builtin_amdgcn_mfma_f32_16x16x32_bf16(af, bfr, A##j, 0, 0, 0); }
      FJ(MFSF)
#undef MFSF
    }
  }

  // ---------------- z (+bias) -> LDS, one barrier ----------------
  // C/D layout: col = (cg+4j)*16 + cl, local row = rg*16 + quad*4 + r
#define WRZ(j) { \
    int col = (cg + 4*(j)) * 16 + cl; \
    if (col < 528) { \
      float bt = (col < CC) ? bias[col] : 0.f; \
      int rr0 = rg * 16 + quad * 4; \
      zs[rr0 + 0][col] = A##j[0] + bt; \
      zs[rr0 + 1][col] = A##j[1] + bt; \
      zs[rr0 + 2][col] = A##j[2] + bt; \
      zs[rr0 + 3][col] = A##j[3] + bt; \
    } }
  FJ(WRZ)
#undef WRZ
  __syncthreads();

  // ---------------- per-wave epilogue: 4 whole rows ----------------
  const int lrow = w * 4;
  const size_t grow = (size_t)(row0 + lrow);

#define LDP(j) float pv##j = ((lane + 64*(j)) < CC) ? pw[lane + 64*(j)] : 1.f;
  FJ(LDP)
#undef LDP

#define DZ(r,j) float Z##r##_##j = -1e30f;
  FRJ(DZ)
#undef DZ
  unsigned ym0 = 0, ym1 = 0, ym2 = 0, ym3 = 0;
  float lossloc = 0.f;

#define EPI(r,j) { \
    int col = lane + 64*(j); \
    if (col < CC) { \
      float z = zs[lrow + (r)][col]; \
      Z##r##_##j = z; \
      float yv = __builtin_nontemporal_load(&y[(grow + (r)) * CC + col]); \
      float l1 = LOG2F(1.f + EXP2F(fabsf(z) * -1.4426950408889634f)) * 0.6931471805599453f; \
      float sp = fmaxf(z, 0.f) + l1; \
      lossloc += pv##j * yv * (sp - z) + (1.f - yv) * sp; \
      if (yv > 0.5f) ym##r |= (1u << (j)); \
    } }
  FRJ(EPI)
#undef EPI

  // per-row k: popc + full 64-lane butterfly (2 rows packed per u32)
  unsigned kp01 = (unsigned)__popc(ym0) | ((unsigned)__popc(ym1) << 16);
  unsigned kp23 = (unsigned)__popc(ym2) | ((unsigned)__popc(ym3) << 16);
#pragma unroll
  for (int m = 1; m < 64; m <<= 1) {
    kp01 += __shfl_xor(kp01, m, 64);
    kp23 += __shfl_xor(kp23, m, 64);
  }
  const int kr[4] = {(int)(kp01 & 0xffffu), (int)(kp01 >> 16),
                     (int)(kp23 & 0xffffu), (int)(kp23 >> 16)};

  // In-wave bisection, no barriers, early exit (26 iters over [-64,64])
  float lo[4], hi[4], th[4];
  bool fnd[4];
#pragma unroll
  for (int r = 0; r < 4; ++r) { lo[r] = -64.f; hi[r] = 64.f; th[r] = 0.f; fnd[r] = false; }

#pragma unroll 1
  for (int it = 0; it < 26; ++it) {
    float tm[4];
#pragma unroll
    for (int r = 0; r < 4; ++r) tm[r] = 0.5f * (lo[r] + hi[r]);
    int c[4] = {0, 0, 0, 0};
#define CNT(r,j) c[r] += (Z##r##_##j > tm[r]) ? 1 : 0;
    FRJ(CNT)
#undef CNT
    unsigned p01 = (unsigned)c[0] | ((unsigned)c[1] << 16);
    unsigned p23 = (unsigned)c[2] | ((unsigned)c[3] << 16);
#pragma unroll
    for (int m = 1; m < 64; m <<= 1) {
      p01 += __shfl_xor(p01, m, 64);
      p23 += __shfl_xor(p23, m, 64);
    }
    const int tot[4] = {(int)(p01 & 0xffffu), (int)(p01 >> 16),
                        (int)(p23 & 0xffffu), (int)(p23 >> 16)};
#pragma unroll
    for (int r = 0; r < 4; ++r) {
      if (!fnd[r]) {
        if (tot[r] == kr[r])                         { th[r] = tm[r]; fnd[r] = true; }
        else if (tm[r] <= lo[r] || tm[r] >= hi[r])   { th[r] = lo[r]; fnd[r] = true; }
        else if (tot[r] > kr[r])                     lo[r] = tm[r];
        else                                         hi[r] = tm[r];
      }
    }
    if (fnd[0] && fnd[1] && fnd[2] && fnd[3]) break;  // wave-uniform
  }
#pragma unroll
  for (int r = 0; r < 4; ++r) if (!fnd[r]) th[r] = lo[r];

  // hits among positives
  int h[4] = {0, 0, 0, 0};
#define HIT(r,j) if (((ym##r >> (j)) & 1u) && Z##r##_##j > th[r]) h[r]++;
  FRJ(HIT)
#undef HIT
  unsigned q01 = (unsigned)h[0] | ((unsigned)h[1] << 16);
  unsigned q23 = (unsigned)h[2] | ((unsigned)h[3] << 16);
#pragma unroll
  for (int m = 1; m < 64; m <<= 1) {
    q01 += __shfl_xor(q01, m, 64);
    q23 += __shfl_xor(q23, m, 64);
  }
  float scoreloc = 0.f;
  if (lane == 0) {
    const int hh[4] = {(int)(q01 & 0xffffu), (int)(q01 >> 16),
                       (int)(q23 & 0xffffu), (int)(q23 >> 16)};
#pragma unroll
    for (int r = 0; r < 4; ++r) {
      int hv = hh[r] < kr[r] ? hh[r] : kr[r];   // tie/exhaustion clamp
      scoreloc += (float)hv / (float)kr[r];
    }
  }

  // loss: wave butterfly; block: LDS + one atomic per block per output
#pragma unroll
  for (int m = 1; m < 64; m <<= 1) lossloc += __shfl_xor(lossloc, m, 64);
  if (lane == 0) { redL[w] = lossloc; redS[w] = scoreloc; }
  __syncthreads();
  if (tid == 0) {
    float sl = 0.f, ss = 0.f;
#pragma unroll
    for (int i = 0; i < 8; ++i) { sl += redL[i]; ss += redS[i]; }
    atomicAdd(&accum[0], sl);
    atomicAdd(&accum[1], ss);
  }
}

__global__ void wcvt_kernel(const float* __restrict__ W, short* __restrict__ Wbf,
                            float* __restrict__ ws) {
  if (blockIdx.x == 0 && threadIdx.x == 0) { ws[0] = 0.f; ws[1] = 0.f; }
  int idx = (blockIdx.x * 256 + threadIdx.x) * 4;   // elem in [576*512]
  int row = idx >> 9;
  bf16x4 v = {0, 0, 0, 0};
  if (row < CC) {
    f32x4 f = *(const f32x4*)(W + idx);
    v[0]=f2bf(f.x); v[1]=f2bf(f.y); v[2]=f2bf(f.z); v[3]=f2bf(f.w);
  }
  *(bf16x4*)(Wbf + idx) = v;
}

__global__ void init_ws_kernel(float* ws) {
  ws[0] = 0.f;
  ws[1] = 0.f;
}

__global__ void finalize_kernel(const float* __restrict__ ws, float* __restrict__ out) {
  out[0] = (float)((double)ws[0] / ((double)BB * (double)CC));
  out[1] = (float)((double)ws[1] / (double)BB);
}

extern "C" void kernel_launch(void* const* d_in, const int* in_sizes, int n_in,
                              void* d_out, int out_size, void* d_ws, size_t ws_size,
                              hipStream_t stream) {
  const float* x  = (const float*)d_in[0];
  const float* y  = (const float*)d_in[1];
  const float* W  = (const float*)d_in[2];
  const float* b  = (const float*)d_in[3];
  const float* pw = (const float*)d_in[4];
  float* out = (float*)d_out;
  float* ws  = (float*)d_ws;
  short* Wbf = (short*)((char*)d_ws + 64);

  const size_t need = 64 + (size_t)NCOLP * DD * 2;
  const bool pre = (ws_size >= need);

  if (pre) {
    wcvt_kernel<<<dim3(NCOLP * DD / 1024), dim3(256), 0, stream>>>(W, Wbf, ws);
    fused_mfma_bce_topk<true><<<dim3(BB / BM), dim3(512), 0, stream>>>(
        x, y, W, Wbf, b, pw, ws);
  } else {
    init_ws_kernel<<<dim3(1), dim3(1), 0, stream>>>(ws);
    fused_mfma_bce_topk<false><<<dim3(BB / BM), dim3(512), 0, stream>>>(
        x, y, W, Wbf, b, pw, ws);
  }
  finalize_kernel<<<dim3(1), dim3(1), 0, stream>>>(ws, out);
}